// Round 6
// baseline (139.705 us; speedup 1.0000x reference)
//
#include <hip/hip_runtime.h>

// MHA: B=2, S=2048, D=1024, H=16, DH=64. f32 in/out, bf16 MFMA internally.
// wconv_kernel: W q/k/v f32 -> bf16 (read 16x by gemm; convert once).
// proj_kernel:  Q/K/V = X @ W^T. m97-style: 128x128 tile, BK=32, 4 waves,
//               global_load_lds width=16 (no ds_writes), double-buffered 48KB LDS
//               (3 blocks/CU), pre-swizzled global sources so linear LDS +
//               XOR-swizzled reads are conflict-free. A stays f32 in LDS (cvt_pk
//               at fragment read); B bf16. XCD-chunked remap.
//               Q pre-scaled by 0.125*log2(e) for exp2-domain softmax.
// attn_kernel:  causal flash attention (unchanged from round 3).

typedef unsigned short u16;
typedef unsigned int u32;
typedef u16 u16x4 __attribute__((ext_vector_type(4)));
typedef u16 u16x8 __attribute__((ext_vector_type(8)));
typedef u32 u32x2 __attribute__((ext_vector_type(2)));
typedef u32 u32x4 __attribute__((ext_vector_type(4)));
typedef __bf16 bf16x8 __attribute__((ext_vector_type(8)));
typedef float f32x4 __attribute__((ext_vector_type(4)));

static __device__ __forceinline__ u16 f2bf(float f) {
  unsigned u = __builtin_bit_cast(unsigned, f);
  return (u16)((u + 0x7FFFu + ((u >> 16) & 1u)) >> 16);
}

static __device__ __forceinline__ u32 cvt_pk_bf16(float lo, float hi) {
  u32 r;
  asm("v_cvt_pk_bf16_f32 %0, %1, %2" : "=v"(r) : "v"(lo), "v"(hi));
  return r;
}

static __device__ __forceinline__ u16x8 cvt8(float4 f0, float4 f1) {
  u32x4 v;
  v[0] = cvt_pk_bf16(f0.x, f0.y);
  v[1] = cvt_pk_bf16(f0.z, f0.w);
  v[2] = cvt_pk_bf16(f1.x, f1.y);
  v[3] = cvt_pk_bf16(f1.z, f1.w);
  return __builtin_bit_cast(u16x8, v);
}

static __device__ __forceinline__ f32x4 mfma16(u16x8 a, u16x8 b, f32x4 c) {
  return __builtin_amdgcn_mfma_f32_16x16x32_bf16(
      __builtin_bit_cast(bf16x8, a), __builtin_bit_cast(bf16x8, b), c, 0, 0, 0);
}

// async global->LDS, 16B per lane; LDS dest = uniform base + lane*16 (linear)
#define GLOAD16(GSRC, LDST)                                                  \
  __builtin_amdgcn_global_load_lds(                                         \
      (const __attribute__((address_space(1))) unsigned int*)(GSRC),        \
      (__attribute__((address_space(3))) unsigned int*)(LDST), 16, 0, 0)

// ---------------------------------------------------------------- W f32->bf16
__global__ __launch_bounds__(256) void wconv_kernel(
    const float* __restrict__ Wq, const float* __restrict__ Wk,
    const float* __restrict__ Wv, u16* __restrict__ dst) {
  const float* src = (blockIdx.y == 0) ? Wq : (blockIdx.y == 1) ? Wk : Wv;
  u16* d = dst + (size_t)blockIdx.y * (1024 * 1024);
  const int i = (blockIdx.x * 256 + threadIdx.x) * 8;
  const float4 f0 = *(const float4*)(src + i);
  const float4 f1 = *(const float4*)(src + i + 4);
  *(u16x8*)(d + i) = cvt8(f0, f1);
}

// ---------------------------------------------------------------- projections
__global__ __launch_bounds__(256) void proj_kernel(
    const float* __restrict__ Xq, const float* __restrict__ Xk, const float* __restrict__ Xv,
    const u16* __restrict__ Wbf,
    u16* __restrict__ Qb, u16* __restrict__ Kb, u16* __restrict__ Vt) {
  // XCD-chunk remap: 768 = 8*96 (bijective). n fastest => the 8 n-blocks
  // sharing an X-tile run consecutively on ONE XCD (X-tile stays in its L2).
  const int d0 = blockIdx.x;
  const int true_id = (d0 & 7) * 96 + (d0 >> 3);
  const int mode = true_id >> 8;    // 0=Q 1=K 2=V (256 blocks per mode)
  const int rem = true_id & 255;
  const int m0 = (rem >> 3) * 128;  // 32 m-blocks
  const int n0 = (rem & 7) * 128;   // 8 n-blocks

  const float* __restrict__ X = (mode == 0) ? Xq : (mode == 1) ? Xk : Xv;
  const u16* __restrict__ W = Wbf + (size_t)mode * (1024 * 1024);

  // Linear LDS (global_load_lds requirement); swizzle lives in the SOURCE addr.
  __shared__ __align__(16) char As[2][128 * 128];  // f32 [128][32], 128B rows
  __shared__ __align__(16) char Bs[2][128 * 64];   // bf16 [128][32], 64B rows

  const int t = threadIdx.x;
  const int lane = t & 63;
  const int w = t >> 6;  // 4 waves: wm = w>>1, wn = w&1, each 64x64 out
  const int wm = w >> 1, wn = w & 1;
  const int lr = lane & 15, lg = lane >> 4;

  // A staging: 16 instrs of 1KB (8 rows x 8 slots); 4 per wave.
  // LDS slot (r, c) holds X[m0+r, k0 + (c ^ (r&7))*4 f32] (inverse of read XOR).
  const float* aptr[4];
  int alds[4];
#pragma unroll
  for (int jj = 0; jj < 4; ++jj) {
    const int ja = w * 4 + jj;
    const int r = ja * 8 + (lane >> 3);
    const int cs = (lane & 7) ^ (r & 7);
    aptr[jj] = X + (size_t)(m0 + r) * 1024 + cs * 4;
    alds[jj] = ja * 1024;
  }
  // B staging: 8 instrs of 1KB (16 rows x 4 slots); 2 per wave.
  // LDS slot (r, s) holds W[n0+r, k0 + (s ^ ((r>>1)&3))*8 bf16].
  const u16* bptr[2];
  int blds[2];
#pragma unroll
  for (int jj = 0; jj < 2; ++jj) {
    const int jb = w * 2 + jj;
    const int r = jb * 16 + (lane >> 2);
    const int ss = (lane & 3) ^ ((r >> 1) & 3);
    bptr[jj] = W + (size_t)(n0 + r) * 1024 + ss * 8;
    blds[jj] = jb * 1024;
  }

#define GSTAGE(BUF, K0)                                          \
  do {                                                           \
    _Pragma("unroll") for (int jj = 0; jj < 4; ++jj)             \
        GLOAD16(aptr[jj] + (K0), As[BUF] + alds[jj]);            \
    _Pragma("unroll") for (int jj = 0; jj < 2; ++jj)             \
        GLOAD16(bptr[jj] + (K0), Bs[BUF] + blds[jj]);            \
  } while (0)

  f32x4 acc[4][4] = {};

  GSTAGE(0, 0);
  __syncthreads();  // drains vmcnt before first reads

  int cur = 0;
  for (int kt = 0; kt < 32; ++kt) {
    if (kt < 31) GSTAGE(cur ^ 1, (kt + 1) * 32);  // async, in flight over MFMAs

    u16x8 af[4], bfr[4];
#pragma unroll
    for (int mi = 0; mi < 4; ++mi) {  // A frag: f32 -> bf16 at read
      const int row = wm * 64 + mi * 16 + lr;
      const int sw = (row & 7) << 4;
      const f32x4 c0 = *(const f32x4*)(As[cur] + row * 128 + ((lg * 32) ^ sw));
      const f32x4 c1 = *(const f32x4*)(As[cur] + row * 128 + ((lg * 32 + 16) ^ sw));
      u32x4 pk;
      pk[0] = cvt_pk_bf16(c0[0], c0[1]);
      pk[1] = cvt_pk_bf16(c0[2], c0[3]);
      pk[2] = cvt_pk_bf16(c1[0], c1[1]);
      pk[3] = cvt_pk_bf16(c1[2], c1[3]);
      af[mi] = __builtin_bit_cast(u16x8, pk);
    }
#pragma unroll
    for (int ni = 0; ni < 4; ++ni) {
      const int n = wn * 64 + ni * 16 + lr;
      bfr[ni] = *(const u16x8*)(Bs[cur] + n * 64 + ((lg * 16) ^ (((n >> 1) & 3) << 4)));
    }
#pragma unroll
    for (int mi = 0; mi < 4; ++mi)
#pragma unroll
      for (int ni = 0; ni < 4; ++ni)
        acc[mi][ni] = mfma16(af[mi], bfr[ni], acc[mi][ni]);

    __syncthreads();  // drains vmcnt (next tile ready) + lgkm
    cur ^= 1;
  }
#undef GSTAGE

  // epilogue: C row(m) = lg*4 + r, col(n) = lr
#pragma unroll
  for (int mi = 0; mi < 4; ++mi) {
    const int sbase = m0 + wm * 64 + mi * 16 + lg * 4;
    const int b_ = sbase >> 11;
    const int s_ = sbase & 2047;
#pragma unroll
    for (int ni = 0; ni < 4; ++ni) {
      const int n = n0 + wn * 64 + ni * 16 + lr;
      const int h_ = n >> 6, dh = n & 63;
      if (mode == 2) {
        u16x4 pk;
        pk[0] = f2bf(acc[mi][ni][0]);
        pk[1] = f2bf(acc[mi][ni][1]);
        pk[2] = f2bf(acc[mi][ni][2]);
        pk[3] = f2bf(acc[mi][ni][3]);
        *(u16x4*)(Vt + ((size_t)((b_ * 16 + h_) * 64 + dh)) * 2048 + s_) = pk;
      } else {
        // Q: fold 1/sqrt(64) * log2(e) so attn softmax runs in exp2 domain
        const float sc = (mode == 0) ? 0.18033688f : 1.0f;
        u16* dst = (mode == 0 ? Qb : Kb) + (size_t)(b_ * 16 + h_) * (2048 * 64) + dh;
#pragma unroll
        for (int r = 0; r < 4; ++r)
          dst[(size_t)(s_ + r) * 64] = f2bf(acc[mi][ni][r] * sc);
      }
    }
  }
}

// ---------------------------------------------------------------- attention
__global__ __launch_bounds__(256, 4) void attn_kernel(
    const u16* __restrict__ Qb, const u16* __restrict__ Kb, const u16* __restrict__ Vt,
    const int* __restrict__ pad, float* __restrict__ out) {
  const int bh = blockIdx.x;  // x=bh so co-resident blocks span qb values
  const int qb = blockIdx.y;
  const int b = bh >> 4, h = bh & 15;
  const int q0 = qb * 64;
  const u16* Qh = Qb + (size_t)bh * (2048 * 64);
  const u16* Kh = Kb + (size_t)bh * (2048 * 64);
  const u16* Vh = Vt + (size_t)bh * (64 * 2048);
  const int* padb = pad + b * 2048;

  __shared__ u16 Ks[2][64 * 64];  // [kv][d], 128B rows, XOR-swizzled, dbuf
  __shared__ u16 Vs[2][64 * 64];  // [d][kv], 128B rows, XOR-swizzled, dbuf
  __shared__ u16 Ps[4][16 * 64];  // per-wave P [q][kv], 128B rows, swizzled

  const int t = threadIdx.x, lane = t & 63, w = t >> 6;
  const int lr = lane & 15, lg = lane >> 4;
  const int swz = (lr & 7) << 4;
  const int sr = t >> 3, scb = t & 7;  // staging: row, 16B col-block
  const int qwave = q0 + w * 16;       // min q-row of this wave
  const int qlane = qwave + lr;        // this lane's q-row (softmax side)
  const int nsteps = qb + 1;

  // Q B-fragments (lane = Q row lr) live in registers for the whole block
  u16x8 qf[2];
#pragma unroll
  for (int kc = 0; kc < 2; ++kc)
    qf[kc] = *(const u16x8*)(Qh + (size_t)qlane * 64 + kc * 32 + lg * 8);

  f32x4 acc[4] = {};               // O: row q = lg*4+r, col d = dt*16+lr
  float mrow = -1e4f, lsum = 0.f;  // per-lane scalar (q = lr)

  u16x8 kr0, kr1, vr0, vr1;
  const int sb0 = (sr * 128 + scb * 16) ^ ((sr & 7) << 4);
  const int sb1 = ((32 + sr) * 128 + scb * 16) ^ ((sr & 7) << 4);

  // prologue: stage tile 0 into buffer 0
  kr0 = *(const u16x8*)(Kh + (size_t)sr * 64 + scb * 8);
  kr1 = *(const u16x8*)(Kh + (size_t)(32 + sr) * 64 + scb * 8);
  vr0 = *(const u16x8*)(Vh + (size_t)sr * 2048 + scb * 8);
  vr1 = *(const u16x8*)(Vh + (size_t)(32 + sr) * 2048 + scb * 8);
  *(u16x8*)((char*)Ks[0] + sb0) = kr0;
  *(u16x8*)((char*)Ks[0] + sb1) = kr1;
  *(u16x8*)((char*)Vs[0] + sb0) = vr0;
  *(u16x8*)((char*)Vs[0] + sb1) = vr1;
  __syncthreads();

  int cur = 0;
  for (int st = 0; st < nsteps; ++st) {
    const int kv0 = st << 6;
    const bool more = st + 1 < nsteps;
    if (more) {  // issue next tile's global loads early; HBM hides under compute
      const int nv0 = kv0 + 64;
      kr0 = *(const u16x8*)(Kh + (size_t)(nv0 + sr) * 64 + scb * 8);
      kr1 = *(const u16x8*)(Kh + (size_t)(nv0 + 32 + sr) * 64 + scb * 8);
      vr0 = *(const u16x8*)(Vh + (size_t)sr * 2048 + nv0 + scb * 8);
      vr1 = *(const u16x8*)(Vh + (size_t)(32 + sr) * 2048 + nv0 + scb * 8);
    }
    int4 pv4[4];
#pragma unroll
    for (int ct = 0; ct < 4; ++ct)
      pv4[ct] = *(const int4*)(padb + kv0 + ct * 16 + lg * 4);

    const u16* KsC = Ks[cur];
    const u16* VsC = Vs[cur];

    // ---- QK^T swapped: mfma(K,Q) -> lane holds q=lr, kv = ct*16 + lg*4 + r
    f32x4 s4[4] = {};
#pragma unroll
    for (int ct = 0; ct < 4; ++ct) {
      if (kv0 + ct * 16 <= qwave + 15) {  // skip fully-causal-masked tiles (uniform)
#pragma unroll
        for (int kc = 0; kc < 2; ++kc) {
          const int byt = ((ct * 16 + lr) * 128 + kc * 64 + lg * 16) ^ swz;
          const u16x8 kf = *(const u16x8*)((char*)KsC + byt);
          s4[ct] = mfma16(kf, qf[kc], s4[ct]);
        }
      }
    }

    // ---- mask (exactly -1e4 like reference); fast path when nothing masked
    float vv[4][4];
    const int pall = pv4[0].x & pv4[0].y & pv4[0].z & pv4[0].w &
                     pv4[1].x & pv4[1].y & pv4[1].z & pv4[1].w &
                     pv4[2].x & pv4[2].y & pv4[2].z & pv4[2].w &
                     pv4[3].x & pv4[3].y & pv4[3].z & pv4[3].w;
    if ((kv0 + 63 <= qwave) && __all(pall != 0)) {
#pragma unroll
      for (int ct = 0; ct < 4; ++ct)
#pragma unroll
        for (int r = 0; r < 4; ++r) vv[ct][r] = s4[ct][r];
    } else {
      const int lim = qlane - kv0 - lg * 4;  // need ct*16 + r <= lim
#pragma unroll
      for (int ct = 0; ct < 4; ++ct) {
        const int* pvp = (const int*)&pv4[ct];
#pragma unroll
        for (int r = 0; r < 4; ++r)
          vv[ct][r] = (pvp[r] && (ct * 16 + r) <= lim) ? s4[ct][r] : -1e4f;
      }
    }

    // ---- online softmax, fully per-lane (q = lr), 2 shfl per reduce
    float m0 = fmaxf(fmaxf(fmaxf(vv[0][0], vv[0][1]), fmaxf(vv[0][2], vv[0][3])),
                     fmaxf(fmaxf(vv[1][0], vv[1][1]), fmaxf(vv[1][2], vv[1][3])));
    float m1 = fmaxf(fmaxf(fmaxf(vv[2][0], vv[2][1]), fmaxf(vv[2][2], vv[2][3])),
                     fmaxf(fmaxf(vv[3][0], vv[3][1]), fmaxf(vv[3][2], vv[3][3])));
    float mx = fmaxf(m0, m1);
    mx = fmaxf(mx, __shfl_xor(mx, 16));
    mx = fmaxf(mx, __shfl_xor(mx, 32));
    const float mn = fmaxf(mrow, mx);
    const float al = exp2f(mrow - mn);
    mrow = mn;

    float p[4][4];
#pragma unroll
    for (int ct = 0; ct < 4; ++ct)
#pragma unroll
      for (int r = 0; r < 4; ++r) p[ct][r] = exp2f(vv[ct][r] - mn);
    float ps = (((p[0][0] + p[0][1]) + (p[0][2] + p[0][3])) +
                ((p[1][0] + p[1][1]) + (p[1][2] + p[1][3]))) +
               (((p[2][0] + p[2][1]) + (p[2][2] + p[2][3])) +
                ((p[3][0] + p[3][1]) + (p[3][2] + p[3][3])));
    ps += __shfl_xor(ps, 16);
    ps += __shfl_xor(ps, 32);
    lsum = lsum * al + ps;

    // ---- pack P to bf16 and roundtrip through per-wave LDS -> A-fragments
    u16* PsB = &Ps[w][0];
#pragma unroll
    for (int ct = 0; ct < 4; ++ct) {
      u32x2 pw;
      pw[0] = cvt_pk_bf16(p[ct][0], p[ct][1]);
      pw[1] = cvt_pk_bf16(p[ct][2], p[ct][3]);
      const int pb = (lr * 128 + ct * 32 + lg * 8) ^ swz;
      *(u32x2*)((char*)PsB + pb) = pw;
    }
    const u16x8 pa0 = *(const u16x8*)((char*)PsB + ((lr * 128 + lg * 16) ^ swz));
    const u16x8 pa1 = *(const u16x8*)((char*)PsB + ((lr * 128 + 64 + lg * 16) ^ swz));

    // ---- redistribute al to PV layout (lane's q rows = lg*4+r)
    float alv[4];
#pragma unroll
    for (int r = 0; r < 4; ++r)
      alv[r] = __builtin_bit_cast(
          float, __builtin_amdgcn_ds_bpermute((lg * 4 + r) * 4, __builtin_bit_cast(int, al)));

    // ---- PV: O += P.V^T  (C: row=q, col=d)
#pragma unroll
    for (int dt = 0; dt < 4; ++dt) {
#pragma unroll
      for (int r = 0; r < 4; ++r) acc[dt][r] *= alv[r];
      const int r0 = (dt * 16 + lr) * 128;
      acc[dt] = mfma16(pa0, *(const u16x8*)((char*)VsC + ((r0 + lg * 16) ^ swz)), acc[dt]);
      acc[dt] = mfma16(pa1, *(const u16x8*)((char*)VsC + ((r0 + 64 + lg * 16) ^ swz)), acc[dt]);
    }

    if (more) {  // write-late into the other buffer; no reader of it this step
      u16* Kn = Ks[cur ^ 1];
      u16* Vn = Vs[cur ^ 1];
      *(u16x8*)((char*)Kn + sb0) = kr0;
      *(u16x8*)((char*)Kn + sb1) = kr1;
      *(u16x8*)((char*)Vn + sb0) = vr0;
      *(u16x8*)((char*)Vn + sb1) = vr1;
    }
    __syncthreads();
    cur ^= 1;
  }

  // ---- epilogue: out[b][q][h*64+d] = acc/l  (l redistributed like al)
  const float il = 1.0f / lsum;
  float linv[4];
#pragma unroll
  for (int r = 0; r < 4; ++r)
    linv[r] = __builtin_bit_cast(
        float, __builtin_amdgcn_ds_bpermute((lg * 4 + r) * 4, __builtin_bit_cast(int, il)));
  float* obase = out + ((size_t)(b * 2048 + qwave + lg * 4)) * 1024 + h * 64 + lr;
#pragma unroll
  for (int r = 0; r < 4; ++r)
#pragma unroll
    for (int dt = 0; dt < 4; ++dt)
      obase[(size_t)r * 1024 + dt * 16] = acc[dt][r] * linv[r];
}

extern "C" void kernel_launch(void* const* d_in, const int* in_sizes, int n_in,
                              void* d_out, int out_size, void* d_ws, size_t ws_size,
                              hipStream_t stream) {
  const float* q  = (const float*)d_in[0];
  const float* k  = (const float*)d_in[1];
  const float* v  = (const float*)d_in[2];
  const float* wq = (const float*)d_in[3];
  const float* wk = (const float*)d_in[4];
  const float* wv = (const float*)d_in[5];
  const int* pad  = (const int*)d_in[6];
  float* out = (float*)d_out;

  u16* Qb  = (u16*)d_ws;                    // [B,H,S,64] bf16, pre-scaled (8MB)
  u16* Kb  = Qb + (size_t)4 * 1024 * 1024;  // [B,H,S,64] bf16 (8MB)
  u16* Vt  = Kb + (size_t)4 * 1024 * 1024;  // [B,H,64,S] bf16 (8MB)
  u16* Wbf = Vt + (size_t)4 * 1024 * 1024;  // [3][1024][1024] bf16 (6MB)

  dim3 gc(512, 3);
  wconv_kernel<<<gc, 256, 0, stream>>>(wq, wk, wv, Wbf);

  proj_kernel<<<768, 256, 0, stream>>>(q, k, v, Wbf, Qb, Kb, Vt);

  dim3 ga(32, 32);  // x=bh, y=qb
  attn_kernel<<<ga, 256, 0, stream>>>(Qb, Kb, Vt, pad, out);
}

// Round 7
// 113.788 us; speedup vs baseline: 1.2278x; 1.2278x over previous
//
#include <hip/hip_runtime.h>

// MHA: B=2, S=2048, D=1024, H=16, DH=64. f32 in/out, bf16 MFMA internally.
// wconv_kernel: W q/k/v f32 -> bf16 (read 16x by gemm; convert once).
// proj_kernel:  fused Q/K/V = X @ W^T, one launch (768 blocks, 128x128, BK=32).
//               3-buffer LDS ring, depth-3 prefetch, COUNTED vmcnt (never 0 in
//               the loop), raw s_barrier. A: f32 global->reg->cvt->ds_write
//               (write-late); B: global_load_lds width=16. Slot-XOR LDS layout,
//               even bank spread. Q pre-scaled by 0.125*log2(e).
// attn_kernel:  causal flash attention (unchanged from round 3).

typedef unsigned short u16;
typedef unsigned int u32;
typedef u16 u16x4 __attribute__((ext_vector_type(4)));
typedef u16 u16x8 __attribute__((ext_vector_type(8)));
typedef u32 u32x2 __attribute__((ext_vector_type(2)));
typedef u32 u32x4 __attribute__((ext_vector_type(4)));
typedef __bf16 bf16x8 __attribute__((ext_vector_type(8)));
typedef float f32x4 __attribute__((ext_vector_type(4)));

static __device__ __forceinline__ u16 f2bf(float f) {
  unsigned u = __builtin_bit_cast(unsigned, f);
  return (u16)((u + 0x7FFFu + ((u >> 16) & 1u)) >> 16);
}

static __device__ __forceinline__ u32 cvt_pk_bf16(float lo, float hi) {
  u32 r;
  asm("v_cvt_pk_bf16_f32 %0, %1, %2" : "=v"(r) : "v"(lo), "v"(hi));
  return r;
}

static __device__ __forceinline__ u16x8 cvt8(float4 f0, float4 f1) {
  u32x4 v;
  v[0] = cvt_pk_bf16(f0.x, f0.y);
  v[1] = cvt_pk_bf16(f0.z, f0.w);
  v[2] = cvt_pk_bf16(f1.x, f1.y);
  v[3] = cvt_pk_bf16(f1.z, f1.w);
  return __builtin_bit_cast(u16x8, v);
}

static __device__ __forceinline__ f32x4 mfma16(u16x8 a, u16x8 b, f32x4 c) {
  return __builtin_amdgcn_mfma_f32_16x16x32_bf16(
      __builtin_bit_cast(bf16x8, a), __builtin_bit_cast(bf16x8, b), c, 0, 0, 0);
}

// async global->LDS, 16B/lane; LDS dest = wave-uniform base + lane*16 (linear)
#define GLOAD16(GSRC, LDST)                                                  \
  __builtin_amdgcn_global_load_lds(                                         \
      (const __attribute__((address_space(1))) unsigned int*)(GSRC),        \
      (__attribute__((address_space(3))) unsigned int*)(LDST), 16, 0, 0)

#define FENCE() asm volatile("" ::: "memory")
#define BARX()                        \
  do {                                \
    __builtin_amdgcn_s_barrier();     \
    FENCE();                          \
  } while (0)

// ---------------------------------------------------------------- W f32->bf16
__global__ __launch_bounds__(256) void wconv_kernel(
    const float* __restrict__ Wq, const float* __restrict__ Wk,
    const float* __restrict__ Wv, u16* __restrict__ dst) {
  const float* src = (blockIdx.y == 0) ? Wq : (blockIdx.y == 1) ? Wk : Wv;
  u16* d = dst + (size_t)blockIdx.y * (1024 * 1024);
  const int i = (blockIdx.x * 256 + threadIdx.x) * 8;
  const float4 f0 = *(const float4*)(src + i);
  const float4 f1 = *(const float4*)(src + i + 4);
  *(u16x8*)(d + i) = cvt8(f0, f1);
}

// ---------------------------------------------------------------- projections
__global__ __launch_bounds__(256) void proj_kernel(
    const float* __restrict__ Xq, const float* __restrict__ Xk, const float* __restrict__ Xv,
    const u16* __restrict__ Wbf,
    u16* __restrict__ Qb, u16* __restrict__ Kb, u16* __restrict__ Vt) {
  // XCD-chunk remap (768 = 8*96, bijective); n fastest within a chunk so the
  // 24 n-blocks sharing an X m-slice run consecutively on one XCD.
  const int d0 = blockIdx.x;
  const int tid = (d0 & 7) * 96 + (d0 >> 3);
  const int nI = tid % 24, mI = tid / 24;
  const int mode = nI >> 3;        // 0=Q 1=K 2=V
  const int m0 = mI * 128;
  const int n0 = (nI & 7) * 128;   // col within mode's W

  const float* __restrict__ X = (mode == 0) ? Xq : (mode == 1) ? Xk : Xv;
  const u16* __restrict__ W = Wbf + (size_t)mode * (1024 * 1024);

  // bf16 [128 rows][32 k] per tile; 64B rows, slot-XOR: slot = k8 ^ ((row>>1)&3)
  __shared__ __align__(16) u16 As[3][128 * 32];
  __shared__ __align__(16) u16 Bs[3][128 * 32];

  const int t = threadIdx.x;
  const int lane = t & 63;
  const int w = t >> 6;
  const int wm = w >> 1, wn = w & 1;
  const int lr = lane & 15, lg = lane >> 4;

  // staging geometry: thread covers rows srow0/srow1, one 16B slot each
  const int srow0 = w * 32 + (lane >> 2);
  const int srow1 = srow0 + 16;
  const int skoff = ((lane & 3) ^ ((lane >> 3) & 3)) * 8;  // permuted k-slot
  const int ldsb0 = w * 2048 + lane * 16;                  // byte offsets
  const int ldsb1 = ldsb0 + 1024;

  const float* Xr0 = X + (size_t)(m0 + srow0) * 1024 + skoff;
  const float* Xr1 = X + (size_t)(m0 + srow1) * 1024 + skoff;
  const u16* Wr0 = W + (size_t)(n0 + srow0) * 1024 + skoff;
  const u16* Wr1 = W + (size_t)(n0 + srow1) * 1024 + skoff;

  float4 a0_, a1_, a2_, a3_;

#define ISSUE_A(T)                                   \
  do {                                               \
    const float* _p0 = Xr0 + (T) * 32;               \
    const float* _p1 = Xr1 + (T) * 32;               \
    a0_ = ((const float4*)_p0)[0];                   \
    a1_ = ((const float4*)_p0)[1];                   \
    a2_ = ((const float4*)_p1)[0];                   \
    a3_ = ((const float4*)_p1)[1];                   \
  } while (0)
#define WRITE_A(BUF)                                                 \
  do {                                                               \
    *(u16x8*)((char*)As[BUF] + ldsb0) = cvt8(a0_, a1_);              \
    *(u16x8*)((char*)As[BUF] + ldsb1) = cvt8(a2_, a3_);              \
  } while (0)
#define ISSUE_B(T, BUF)                                              \
  do {                                                               \
    GLOAD16(Wr0 + (T) * 32, (char*)Bs[BUF] + w * 2048);              \
    GLOAD16(Wr1 + (T) * 32, (char*)Bs[BUF] + w * 2048 + 1024);       \
  } while (0)

  f32x4 acc[4][4] = {};
  const int rx = (lr >> 1) & 3;  // row bits 1-2 (same for all fragment rows)

#define CMP(BUF)                                                              \
  do {                                                                       \
    u16x8 af[4], bfr[4];                                                     \
    _Pragma("unroll") for (int mi = 0; mi < 4; ++mi) {                        \
      const int row = wm * 64 + mi * 16 + lr;                                \
      af[mi] = *(const u16x8*)((char*)As[BUF] + row * 64 + ((lg ^ rx) << 4)); \
    }                                                                         \
    _Pragma("unroll") for (int ni = 0; ni < 4; ++ni) {                        \
      const int row = wn * 64 + ni * 16 + lr;                                \
      bfr[ni] = *(const u16x8*)((char*)Bs[BUF] + row * 64 + ((lg ^ rx) << 4));\
    }                                                                         \
    _Pragma("unroll") for (int mi = 0; mi < 4; ++mi)                          \
        _Pragma("unroll") for (int ni = 0; ni < 4; ++ni)                      \
            acc[mi][ni] = mfma16(af[mi], bfr[ni], acc[mi][ni]);               \
  } while (0)

  // ---- prologue: tiles 0,1 written; tile 2 A-regs + B(0),B(1) in flight
  ISSUE_A(0); WRITE_A(0);
  ISSUE_A(1); WRITE_A(1);
  ISSUE_A(2);                 // 4 outstanding
  ISSUE_B(0, 0);              // +2
  ISSUE_B(1, 1);              // +2 -> 8
  asm volatile("s_waitcnt vmcnt(2) lgkmcnt(0)" ::: "memory");  // B(0)+A(2) done
  BARX();

  // ---- iter 0 (peeled)
  CMP(0);
  BARX();
  WRITE_A(2);                 // A(2) regs already drained
  ISSUE_A(3);
  ISSUE_B(2, 2);

  // ---- steady: counted waits, loads for t+1,t+2 stay in flight
  for (int tt = 1; tt <= 29; ++tt) {
    asm volatile("s_waitcnt vmcnt(6) lgkmcnt(0)" ::: "memory");  // tile tt ready
    BARX();
    CMP(tt % 3);
    BARX();
    WRITE_A((tt + 2) % 3);    // compiler auto-waits the A regs (vmcnt leaves B in flight)
    if (tt < 29) ISSUE_A(tt + 3);
    ISSUE_B(tt + 2, (tt + 2) % 3);
  }

  // ---- tails
  asm volatile("s_waitcnt vmcnt(2) lgkmcnt(0)" ::: "memory");  // B(30) ready
  BARX();
  CMP(30 % 3);
  asm volatile("s_waitcnt vmcnt(0) lgkmcnt(0)" ::: "memory");  // B(31) ready
  BARX();
  CMP(31 % 3);
#undef ISSUE_A
#undef WRITE_A
#undef ISSUE_B
#undef CMP

  // epilogue: C row(m) = lg*4 + r, col(n) = lr
#pragma unroll
  for (int mi = 0; mi < 4; ++mi) {
    const int sbase = m0 + wm * 64 + mi * 16 + lg * 4;
    const int b_ = sbase >> 11;
    const int s_ = sbase & 2047;
#pragma unroll
    for (int ni = 0; ni < 4; ++ni) {
      const int n = n0 + wn * 64 + ni * 16 + lr;  // 0..1023 within mode
      const int h_ = n >> 6, dh = n & 63;
      if (mode == 2) {
        u16x4 pk;
        pk[0] = f2bf(acc[mi][ni][0]);
        pk[1] = f2bf(acc[mi][ni][1]);
        pk[2] = f2bf(acc[mi][ni][2]);
        pk[3] = f2bf(acc[mi][ni][3]);
        *(u16x4*)(Vt + ((size_t)((b_ * 16 + h_) * 64 + dh)) * 2048 + s_) = pk;
      } else {
        // Q: fold 1/sqrt(64) * log2(e) so attn softmax runs in exp2 domain
        const float sc = (mode == 0) ? 0.18033688f : 1.0f;
        u16* dst = (mode == 0 ? Qb : Kb) + (size_t)(b_ * 16 + h_) * (2048 * 64) + dh;
#pragma unroll
        for (int r = 0; r < 4; ++r)
          dst[(size_t)(s_ + r) * 64] = f2bf(acc[mi][ni][r] * sc);
      }
    }
  }
}

// ---------------------------------------------------------------- attention
__global__ __launch_bounds__(256, 4) void attn_kernel(
    const u16* __restrict__ Qb, const u16* __restrict__ Kb, const u16* __restrict__ Vt,
    const int* __restrict__ pad, float* __restrict__ out) {
  const int bh = blockIdx.x;  // x=bh so co-resident blocks span qb values
  const int qb = blockIdx.y;
  const int b = bh >> 4, h = bh & 15;
  const int q0 = qb * 64;
  const u16* Qh = Qb + (size_t)bh * (2048 * 64);
  const u16* Kh = Kb + (size_t)bh * (2048 * 64);
  const u16* Vh = Vt + (size_t)bh * (64 * 2048);
  const int* padb = pad + b * 2048;

  __shared__ u16 Ks[2][64 * 64];  // [kv][d], 128B rows, XOR-swizzled, dbuf
  __shared__ u16 Vs[2][64 * 64];  // [d][kv], 128B rows, XOR-swizzled, dbuf
  __shared__ u16 Ps[4][16 * 64];  // per-wave P [q][kv], 128B rows, swizzled

  const int t = threadIdx.x, lane = t & 63, w = t >> 6;
  const int lr = lane & 15, lg = lane >> 4;
  const int swz = (lr & 7) << 4;
  const int sr = t >> 3, scb = t & 7;  // staging: row, 16B col-block
  const int qwave = q0 + w * 16;       // min q-row of this wave
  const int qlane = qwave + lr;        // this lane's q-row (softmax side)
  const int nsteps = qb + 1;

  // Q B-fragments (lane = Q row lr) live in registers for the whole block
  u16x8 qf[2];
#pragma unroll
  for (int kc = 0; kc < 2; ++kc)
    qf[kc] = *(const u16x8*)(Qh + (size_t)qlane * 64 + kc * 32 + lg * 8);

  f32x4 acc[4] = {};               // O: row q = lg*4+r, col d = dt*16+lr
  float mrow = -1e4f, lsum = 0.f;  // per-lane scalar (q = lr)

  u16x8 kr0, kr1, vr0, vr1;
  const int sb0 = (sr * 128 + scb * 16) ^ ((sr & 7) << 4);
  const int sb1 = ((32 + sr) * 128 + scb * 16) ^ ((sr & 7) << 4);

  // prologue: stage tile 0 into buffer 0
  kr0 = *(const u16x8*)(Kh + (size_t)sr * 64 + scb * 8);
  kr1 = *(const u16x8*)(Kh + (size_t)(32 + sr) * 64 + scb * 8);
  vr0 = *(const u16x8*)(Vh + (size_t)sr * 2048 + scb * 8);
  vr1 = *(const u16x8*)(Vh + (size_t)(32 + sr) * 2048 + scb * 8);
  *(u16x8*)((char*)Ks[0] + sb0) = kr0;
  *(u16x8*)((char*)Ks[0] + sb1) = kr1;
  *(u16x8*)((char*)Vs[0] + sb0) = vr0;
  *(u16x8*)((char*)Vs[0] + sb1) = vr1;
  __syncthreads();

  int cur = 0;
  for (int st = 0; st < nsteps; ++st) {
    const int kv0 = st << 6;
    const bool more = st + 1 < nsteps;
    if (more) {  // issue next tile's global loads early; HBM hides under compute
      const int nv0 = kv0 + 64;
      kr0 = *(const u16x8*)(Kh + (size_t)(nv0 + sr) * 64 + scb * 8);
      kr1 = *(const u16x8*)(Kh + (size_t)(nv0 + 32 + sr) * 64 + scb * 8);
      vr0 = *(const u16x8*)(Vh + (size_t)sr * 2048 + nv0 + scb * 8);
      vr1 = *(const u16x8*)(Vh + (size_t)(32 + sr) * 2048 + nv0 + scb * 8);
    }
    int4 pv4[4];
#pragma unroll
    for (int ct = 0; ct < 4; ++ct)
      pv4[ct] = *(const int4*)(padb + kv0 + ct * 16 + lg * 4);

    const u16* KsC = Ks[cur];
    const u16* VsC = Vs[cur];

    // ---- QK^T swapped: mfma(K,Q) -> lane holds q=lr, kv = ct*16 + lg*4 + r
    f32x4 s4[4] = {};
#pragma unroll
    for (int ct = 0; ct < 4; ++ct) {
      if (kv0 + ct * 16 <= qwave + 15) {  // skip fully-causal-masked tiles (uniform)
#pragma unroll
        for (int kc = 0; kc < 2; ++kc) {
          const int byt = ((ct * 16 + lr) * 128 + kc * 64 + lg * 16) ^ swz;
          const u16x8 kf = *(const u16x8*)((char*)KsC + byt);
          s4[ct] = mfma16(kf, qf[kc], s4[ct]);
        }
      }
    }

    // ---- mask (exactly -1e4 like reference); fast path when nothing masked
    float vv[4][4];
    const int pall = pv4[0].x & pv4[0].y & pv4[0].z & pv4[0].w &
                     pv4[1].x & pv4[1].y & pv4[1].z & pv4[1].w &
                     pv4[2].x & pv4[2].y & pv4[2].z & pv4[2].w &
                     pv4[3].x & pv4[3].y & pv4[3].z & pv4[3].w;
    if ((kv0 + 63 <= qwave) && __all(pall != 0)) {
#pragma unroll
      for (int ct = 0; ct < 4; ++ct)
#pragma unroll
        for (int r = 0; r < 4; ++r) vv[ct][r] = s4[ct][r];
    } else {
      const int lim = qlane - kv0 - lg * 4;  // need ct*16 + r <= lim
#pragma unroll
      for (int ct = 0; ct < 4; ++ct) {
        const int* pvp = (const int*)&pv4[ct];
#pragma unroll
        for (int r = 0; r < 4; ++r)
          vv[ct][r] = (pvp[r] && (ct * 16 + r) <= lim) ? s4[ct][r] : -1e4f;
      }
    }

    // ---- online softmax, fully per-lane (q = lr), 2 shfl per reduce
    float m0 = fmaxf(fmaxf(fmaxf(vv[0][0], vv[0][1]), fmaxf(vv[0][2], vv[0][3])),
                     fmaxf(fmaxf(vv[1][0], vv[1][1]), fmaxf(vv[1][2], vv[1][3])));
    float m1 = fmaxf(fmaxf(fmaxf(vv[2][0], vv[2][1]), fmaxf(vv[2][2], vv[2][3])),
                     fmaxf(fmaxf(vv[3][0], vv[3][1]), fmaxf(vv[3][2], vv[3][3])));
    float mx = fmaxf(m0, m1);
    mx = fmaxf(mx, __shfl_xor(mx, 16));
    mx = fmaxf(mx, __shfl_xor(mx, 32));
    const float mn = fmaxf(mrow, mx);
    const float al = exp2f(mrow - mn);
    mrow = mn;

    float p[4][4];
#pragma unroll
    for (int ct = 0; ct < 4; ++ct)
#pragma unroll
      for (int r = 0; r < 4; ++r) p[ct][r] = exp2f(vv[ct][r] - mn);
    float ps = (((p[0][0] + p[0][1]) + (p[0][2] + p[0][3])) +
                ((p[1][0] + p[1][1]) + (p[1][2] + p[1][3]))) +
               (((p[2][0] + p[2][1]) + (p[2][2] + p[2][3])) +
                ((p[3][0] + p[3][1]) + (p[3][2] + p[3][3])));
    ps += __shfl_xor(ps, 16);
    ps += __shfl_xor(ps, 32);
    lsum = lsum * al + ps;

    // ---- pack P to bf16 and roundtrip through per-wave LDS -> A-fragments
    u16* PsB = &Ps[w][0];
#pragma unroll
    for (int ct = 0; ct < 4; ++ct) {
      u32x2 pw;
      pw[0] = cvt_pk_bf16(p[ct][0], p[ct][1]);
      pw[1] = cvt_pk_bf16(p[ct][2], p[ct][3]);
      const int pb = (lr * 128 + ct * 32 + lg * 8) ^ swz;
      *(u32x2*)((char*)PsB + pb) = pw;
    }
    const u16x8 pa0 = *(const u16x8*)((char*)PsB + ((lr * 128 + lg * 16) ^ swz));
    const u16x8 pa1 = *(const u16x8*)((char*)PsB + ((lr * 128 + 64 + lg * 16) ^ swz));

    // ---- redistribute al to PV layout (lane's q rows = lg*4+r)
    float alv[4];
#pragma unroll
    for (int r = 0; r < 4; ++r)
      alv[r] = __builtin_bit_cast(
          float, __builtin_amdgcn_ds_bpermute((lg * 4 + r) * 4, __builtin_bit_cast(int, al)));

    // ---- PV: O += P.V^T  (C: row=q, col=d)
#pragma unroll
    for (int dt = 0; dt < 4; ++dt) {
#pragma unroll
      for (int r = 0; r < 4; ++r) acc[dt][r] *= alv[r];
      const int r0 = (dt * 16 + lr) * 128;
      acc[dt] = mfma16(pa0, *(const u16x8*)((char*)VsC + ((r0 + lg * 16) ^ swz)), acc[dt]);
      acc[dt] = mfma16(pa1, *(const u16x8*)((char*)VsC + ((r0 + 64 + lg * 16) ^ swz)), acc[dt]);
    }

    if (more) {  // write-late into the other buffer; no reader of it this step
      u16* Kn = Ks[cur ^ 1];
      u16* Vn = Vs[cur ^ 1];
      *(u16x8*)((char*)Kn + sb0) = kr0;
      *(u16x8*)((char*)Kn + sb1) = kr1;
      *(u16x8*)((char*)Vn + sb0) = vr0;
      *(u16x8*)((char*)Vn + sb1) = vr1;
    }
    __syncthreads();
    cur ^= 1;
  }

  // ---- epilogue: out[b][q][h*64+d] = acc/l  (l redistributed like al)
  const float il = 1.0f / lsum;
  float linv[4];
#pragma unroll
  for (int r = 0; r < 4; ++r)
    linv[r] = __builtin_bit_cast(
        float, __builtin_amdgcn_ds_bpermute((lg * 4 + r) * 4, __builtin_bit_cast(int, il)));
  float* obase = out + ((size_t)(b * 2048 + qwave + lg * 4)) * 1024 + h * 64 + lr;
#pragma unroll
  for (int r = 0; r < 4; ++r)
#pragma unroll
    for (int dt = 0; dt < 4; ++dt)
      obase[(size_t)r * 1024 + dt * 16] = acc[dt][r] * linv[r];
}

extern "C" void kernel_launch(void* const* d_in, const int* in_sizes, int n_in,
                              void* d_out, int out_size, void* d_ws, size_t ws_size,
                              hipStream_t stream) {
  const float* q  = (const float*)d_in[0];
  const float* k  = (const float*)d_in[1];
  const float* v  = (const float*)d_in[2];
  const float* wq = (const float*)d_in[3];
  const float* wk = (const float*)d_in[4];
  const float* wv = (const float*)d_in[5];
  const int* pad  = (const int*)d_in[6];
  float* out = (float*)d_out;

  u16* Qb  = (u16*)d_ws;                    // [B,H,S,64] bf16, pre-scaled (8MB)
  u16* Kb  = Qb + (size_t)4 * 1024 * 1024;  // [B,H,S,64] bf16 (8MB)
  u16* Vt  = Kb + (size_t)4 * 1024 * 1024;  // [B,H,64,S] bf16 (8MB)
  u16* Wbf = Vt + (size_t)4 * 1024 * 1024;  // [3][1024][1024] bf16 (6MB)

  dim3 gc(512, 3);
  wconv_kernel<<<gc, 256, 0, stream>>>(wq, wk, wv, Wbf);

  proj_kernel<<<768, 256, 0, stream>>>(q, k, v, Wbf, Qb, Kb, Vt);

  dim3 ga(32, 32);  // x=bh, y=qb
  attn_kernel<<<ga, 256, 0, stream>>>(Qb, Kb, Vt, pad, out);
}

// Round 8
// 98.979 us; speedup vs baseline: 1.4115x; 1.1496x over previous
//
#include <hip/hip_runtime.h>

// MHA: B=2, S=2048, D=1024, H=16, DH=64. f32 in/out, bf16 MFMA internally.
// wconv_kernel: W q/k/v f32 -> bf16 (read 16x by gemm; convert once).
// proj_kernel:  fused Q/K/V = X @ W^T (768 blocks, 128x128, BK=32), 3-buffer LDS
//               ring, depth-3 prefetch, counted vmcnt, raw s_barrier (round 7).
// attn_kernel:  causal flash attention, PAIRED q-tiles (hi=31-pi, lo=pi) share
//               staged K/V tiles + barriers -> constant 33 MFMA-steps/block,
//               defer-max rescale (THR=8, exp2 domain), setprio around MFMA.

typedef unsigned short u16;
typedef unsigned int u32;
typedef u16 u16x4 __attribute__((ext_vector_type(4)));
typedef u16 u16x8 __attribute__((ext_vector_type(8)));
typedef u32 u32x2 __attribute__((ext_vector_type(2)));
typedef u32 u32x4 __attribute__((ext_vector_type(4)));
typedef __bf16 bf16x8 __attribute__((ext_vector_type(8)));
typedef float f32x4 __attribute__((ext_vector_type(4)));

static __device__ __forceinline__ u16 f2bf(float f) {
  unsigned u = __builtin_bit_cast(unsigned, f);
  return (u16)((u + 0x7FFFu + ((u >> 16) & 1u)) >> 16);
}

static __device__ __forceinline__ u32 cvt_pk_bf16(float lo, float hi) {
  u32 r;
  asm("v_cvt_pk_bf16_f32 %0, %1, %2" : "=v"(r) : "v"(lo), "v"(hi));
  return r;
}

static __device__ __forceinline__ u16x8 cvt8(float4 f0, float4 f1) {
  u32x4 v;
  v[0] = cvt_pk_bf16(f0.x, f0.y);
  v[1] = cvt_pk_bf16(f0.z, f0.w);
  v[2] = cvt_pk_bf16(f1.x, f1.y);
  v[3] = cvt_pk_bf16(f1.z, f1.w);
  return __builtin_bit_cast(u16x8, v);
}

static __device__ __forceinline__ f32x4 mfma16(u16x8 a, u16x8 b, f32x4 c) {
  return __builtin_amdgcn_mfma_f32_16x16x32_bf16(
      __builtin_bit_cast(bf16x8, a), __builtin_bit_cast(bf16x8, b), c, 0, 0, 0);
}

static __device__ __forceinline__ float bperm_f(int lane, float v) {
  return __builtin_bit_cast(
      float, __builtin_amdgcn_ds_bpermute(lane * 4, __builtin_bit_cast(int, v)));
}

// async global->LDS, 16B/lane; LDS dest = wave-uniform base + lane*16 (linear)
#define GLOAD16(GSRC, LDST)                                                  \
  __builtin_amdgcn_global_load_lds(                                         \
      (const __attribute__((address_space(1))) unsigned int*)(GSRC),        \
      (__attribute__((address_space(3))) unsigned int*)(LDST), 16, 0, 0)

#define FENCE() asm volatile("" ::: "memory")
#define BARX()                        \
  do {                                \
    __builtin_amdgcn_s_barrier();     \
    FENCE();                          \
  } while (0)

// ---------------------------------------------------------------- W f32->bf16
__global__ __launch_bounds__(256) void wconv_kernel(
    const float* __restrict__ Wq, const float* __restrict__ Wk,
    const float* __restrict__ Wv, u16* __restrict__ dst) {
  const float* src = (blockIdx.y == 0) ? Wq : (blockIdx.y == 1) ? Wk : Wv;
  u16* d = dst + (size_t)blockIdx.y * (1024 * 1024);
  const int i = (blockIdx.x * 256 + threadIdx.x) * 8;
  const float4 f0 = *(const float4*)(src + i);
  const float4 f1 = *(const float4*)(src + i + 4);
  *(u16x8*)(d + i) = cvt8(f0, f1);
}

// ---------------------------------------------------------------- projections
__global__ __launch_bounds__(256) void proj_kernel(
    const float* __restrict__ Xq, const float* __restrict__ Xk, const float* __restrict__ Xv,
    const u16* __restrict__ Wbf,
    u16* __restrict__ Qb, u16* __restrict__ Kb, u16* __restrict__ Vt) {
  const int d0 = blockIdx.x;
  const int tid = (d0 & 7) * 96 + (d0 >> 3);
  const int nI = tid % 24, mI = tid / 24;
  const int mode = nI >> 3;        // 0=Q 1=K 2=V
  const int m0 = mI * 128;
  const int n0 = (nI & 7) * 128;

  const float* __restrict__ X = (mode == 0) ? Xq : (mode == 1) ? Xk : Xv;
  const u16* __restrict__ W = Wbf + (size_t)mode * (1024 * 1024);

  __shared__ __align__(16) u16 As[3][128 * 32];
  __shared__ __align__(16) u16 Bs[3][128 * 32];

  const int t = threadIdx.x;
  const int lane = t & 63;
  const int w = t >> 6;
  const int wm = w >> 1, wn = w & 1;
  const int lr = lane & 15, lg = lane >> 4;

  const int srow0 = w * 32 + (lane >> 2);
  const int srow1 = srow0 + 16;
  const int skoff = ((lane & 3) ^ ((lane >> 3) & 3)) * 8;
  const int ldsb0 = w * 2048 + lane * 16;
  const int ldsb1 = ldsb0 + 1024;

  const float* Xr0 = X + (size_t)(m0 + srow0) * 1024 + skoff;
  const float* Xr1 = X + (size_t)(m0 + srow1) * 1024 + skoff;
  const u16* Wr0 = W + (size_t)(n0 + srow0) * 1024 + skoff;
  const u16* Wr1 = W + (size_t)(n0 + srow1) * 1024 + skoff;

  float4 a0_, a1_, a2_, a3_;

#define ISSUE_A(T)                                   \
  do {                                               \
    const float* _p0 = Xr0 + (T) * 32;               \
    const float* _p1 = Xr1 + (T) * 32;               \
    a0_ = ((const float4*)_p0)[0];                   \
    a1_ = ((const float4*)_p0)[1];                   \
    a2_ = ((const float4*)_p1)[0];                   \
    a3_ = ((const float4*)_p1)[1];                   \
  } while (0)
#define WRITE_A(BUF)                                                 \
  do {                                                               \
    *(u16x8*)((char*)As[BUF] + ldsb0) = cvt8(a0_, a1_);              \
    *(u16x8*)((char*)As[BUF] + ldsb1) = cvt8(a2_, a3_);              \
  } while (0)
#define ISSUE_B(T, BUF)                                              \
  do {                                                               \
    GLOAD16(Wr0 + (T) * 32, (char*)Bs[BUF] + w * 2048);              \
    GLOAD16(Wr1 + (T) * 32, (char*)Bs[BUF] + w * 2048 + 1024);       \
  } while (0)

  f32x4 acc[4][4] = {};
  const int rx = (lr >> 1) & 3;

#define CMP(BUF)                                                              \
  do {                                                                       \
    u16x8 af[4], bfr[4];                                                     \
    _Pragma("unroll") for (int mi = 0; mi < 4; ++mi) {                        \
      const int row = wm * 64 + mi * 16 + lr;                                \
      af[mi] = *(const u16x8*)((char*)As[BUF] + row * 64 + ((lg ^ rx) << 4)); \
    }                                                                         \
    _Pragma("unroll") for (int ni = 0; ni < 4; ++ni) {                        \
      const int row = wn * 64 + ni * 16 + lr;                                \
      bfr[ni] = *(const u16x8*)((char*)Bs[BUF] + row * 64 + ((lg ^ rx) << 4));\
    }                                                                         \
    _Pragma("unroll") for (int mi = 0; mi < 4; ++mi)                          \
        _Pragma("unroll") for (int ni = 0; ni < 4; ++ni)                      \
            acc[mi][ni] = mfma16(af[mi], bfr[ni], acc[mi][ni]);               \
  } while (0)

  ISSUE_A(0); WRITE_A(0);
  ISSUE_A(1); WRITE_A(1);
  ISSUE_A(2);
  ISSUE_B(0, 0);
  ISSUE_B(1, 1);
  asm volatile("s_waitcnt vmcnt(2) lgkmcnt(0)" ::: "memory");
  BARX();

  CMP(0);
  BARX();
  WRITE_A(2);
  ISSUE_A(3);
  ISSUE_B(2, 2);

  for (int tt = 1; tt <= 29; ++tt) {
    asm volatile("s_waitcnt vmcnt(6) lgkmcnt(0)" ::: "memory");
    BARX();
    CMP(tt % 3);
    BARX();
    WRITE_A((tt + 2) % 3);
    if (tt < 29) ISSUE_A(tt + 3);
    ISSUE_B(tt + 2, (tt + 2) % 3);
  }

  asm volatile("s_waitcnt vmcnt(2) lgkmcnt(0)" ::: "memory");
  BARX();
  CMP(30 % 3);
  asm volatile("s_waitcnt vmcnt(0) lgkmcnt(0)" ::: "memory");
  BARX();
  CMP(31 % 3);
#undef ISSUE_A
#undef WRITE_A
#undef ISSUE_B
#undef CMP

#pragma unroll
  for (int mi = 0; mi < 4; ++mi) {
    const int sbase = m0 + wm * 64 + mi * 16 + lg * 4;
    const int b_ = sbase >> 11;
    const int s_ = sbase & 2047;
#pragma unroll
    for (int ni = 0; ni < 4; ++ni) {
      const int n = n0 + wn * 64 + ni * 16 + lr;
      const int h_ = n >> 6, dh = n & 63;
      if (mode == 2) {
        u16x4 pk;
        pk[0] = f2bf(acc[mi][ni][0]);
        pk[1] = f2bf(acc[mi][ni][1]);
        pk[2] = f2bf(acc[mi][ni][2]);
        pk[3] = f2bf(acc[mi][ni][3]);
        *(u16x4*)(Vt + ((size_t)((b_ * 16 + h_) * 64 + dh)) * 2048 + s_) = pk;
      } else {
        const float sc = (mode == 0) ? 0.18033688f : 1.0f;
        u16* dst = (mode == 0 ? Qb : Kb) + (size_t)(b_ * 16 + h_) * (2048 * 64) + dh;
#pragma unroll
        for (int r = 0; r < 4; ++r)
          dst[(size_t)(s_ + r) * 64] = f2bf(acc[mi][ni][r] * sc);
      }
    }
  }
}

// ---------------------------------------------------------------- attention
__global__ __launch_bounds__(256, 2) void attn_kernel(
    const u16* __restrict__ Qb, const u16* __restrict__ Kb, const u16* __restrict__ Vt,
    const int* __restrict__ pad, float* __restrict__ out) {
  // Paired q-tiles: block does qbA=31-pi (kv 0..qbA) and qbB=pi (kv 0..qbB),
  // sharing staged K/V. MFMA-steps = 33 const. Block id and id+256 land on the
  // same CU (round-robin) and get pi = p and 15-p -> loop-length sum 49 const.
  const int id = blockIdx.x;
  const int g = id >> 8, r_ = id & 255;
  const int bh = r_ & 31;
  const int p8 = r_ >> 5;
  const int pi = g ? (15 - p8) : p8;
  const int qbA = 31 - pi, qbB = pi;

  const int b = bh >> 4, h = bh & 15;
  const u16* Qh = Qb + (size_t)bh * (2048 * 64);
  const u16* Kh = Kb + (size_t)bh * (2048 * 64);
  const u16* Vh = Vt + (size_t)bh * (64 * 2048);
  const int* padb = pad + b * 2048;

  __shared__ u16 Ks[2][64 * 64];  // [kv][d], 128B rows, XOR-swizzled, dbuf
  __shared__ u16 Vs[2][64 * 64];  // [d][kv], 128B rows, XOR-swizzled, dbuf
  __shared__ u16 Ps[4][16 * 64];  // per-wave P scratch (reused by both tiles)

  const int t = threadIdx.x, lane = t & 63, w = t >> 6;
  const int lr = lane & 15, lg = lane >> 4;
  const int swz = (lr & 7) << 4;
  const int sr = t >> 3, scb = t & 7;
  const int qwaveA = qbA * 64 + w * 16, qwaveB = qbB * 64 + w * 16;

  // Q fragments for both tiles (lane = q-row lr)
  u16x8 qfA[2], qfB[2];
#pragma unroll
  for (int kc = 0; kc < 2; ++kc) {
    qfA[kc] = *(const u16x8*)(Qh + (size_t)(qwaveA + lr) * 64 + kc * 32 + lg * 8);
    qfB[kc] = *(const u16x8*)(Qh + (size_t)(qwaveB + lr) * 64 + kc * 32 + lg * 8);
  }

  f32x4 accA[4] = {}, accB[4] = {};
  float mrowA = -1e4f, lsumA = 0.f, mrowB = -1e4f, lsumB = 0.f;

  u16x8 kr0, kr1, vr0, vr1;
  const int sb0 = (sr * 128 + scb * 16) ^ ((sr & 7) << 4);
  const int sb1 = ((32 + sr) * 128 + scb * 16) ^ ((sr & 7) << 4);

  kr0 = *(const u16x8*)(Kh + (size_t)sr * 64 + scb * 8);
  kr1 = *(const u16x8*)(Kh + (size_t)(32 + sr) * 64 + scb * 8);
  vr0 = *(const u16x8*)(Vh + (size_t)sr * 2048 + scb * 8);
  vr1 = *(const u16x8*)(Vh + (size_t)(32 + sr) * 2048 + scb * 8);
  *(u16x8*)((char*)Ks[0] + sb0) = kr0;
  *(u16x8*)((char*)Ks[0] + sb1) = kr1;
  *(u16x8*)((char*)Vs[0] + sb0) = vr0;
  *(u16x8*)((char*)Vs[0] + sb1) = vr1;
  __syncthreads();

// one q-tile's QK^T + online softmax (defer-max) + PV for the current kv step
#define PROCESS(QF, ACC, MROW, LSUM, QWAVE)                                    \
  do {                                                                         \
    f32x4 s4[4] = {};                                                          \
    __builtin_amdgcn_s_setprio(1);                                             \
    _Pragma("unroll") for (int ct = 0; ct < 4; ++ct) {                         \
      if (kv0 + ct * 16 <= (QWAVE) + 15) {                                     \
        _Pragma("unroll") for (int kc = 0; kc < 2; ++kc) {                     \
          const int byt = ((ct * 16 + lr) * 128 + kc * 64 + lg * 16) ^ swz;    \
          const u16x8 kf = *(const u16x8*)((char*)KsC + byt);                  \
          s4[ct] = mfma16(kf, QF[kc], s4[ct]);                                 \
        }                                                                      \
      }                                                                        \
    }                                                                          \
    __builtin_amdgcn_s_setprio(0);                                             \
    float vv[4][4];                                                            \
    if ((kv0 + 63 <= (QWAVE)) && allpad) {                                     \
      _Pragma("unroll") for (int ct = 0; ct < 4; ++ct)                         \
          _Pragma("unroll") for (int rr = 0; rr < 4; ++rr)                     \
              vv[ct][rr] = s4[ct][rr];                                         \
    } else {                                                                   \
      const int lim = (QWAVE) + lr - kv0 - lg * 4;                             \
      _Pragma("unroll") for (int ct = 0; ct < 4; ++ct) {                       \
        const int* pvp = (const int*)&pv4[ct];                                 \
        _Pragma("unroll") for (int rr = 0; rr < 4; ++rr)                       \
            vv[ct][rr] = (pvp[rr] && (ct * 16 + rr) <= lim) ? s4[ct][rr]       \
                                                            : -1e4f;           \
      }                                                                        \
    }                                                                          \
    float m0_ = fmaxf(fmaxf(fmaxf(vv[0][0], vv[0][1]), fmaxf(vv[0][2], vv[0][3])), \
                      fmaxf(fmaxf(vv[1][0], vv[1][1]), fmaxf(vv[1][2], vv[1][3]))); \
    float m1_ = fmaxf(fmaxf(fmaxf(vv[2][0], vv[2][1]), fmaxf(vv[2][2], vv[2][3])), \
                      fmaxf(fmaxf(vv[3][0], vv[3][1]), fmaxf(vv[3][2], vv[3][3]))); \
    float mx = fmaxf(m0_, m1_);                                                \
    mx = fmaxf(mx, __shfl_xor(mx, 16));                                        \
    mx = fmaxf(mx, __shfl_xor(mx, 32));                                        \
    if (!__all(mx <= (MROW) + 8.0f)) { /* defer-max: rescale only when needed */\
      const float mn = fmaxf((MROW), mx);                                      \
      const float al = exp2f((MROW) - mn);                                     \
      (MROW) = mn;                                                             \
      (LSUM) *= al;                                                            \
      _Pragma("unroll") for (int rr = 0; rr < 4; ++rr) {                       \
        const float alv = bperm_f(lg * 4 + rr, al);                            \
        _Pragma("unroll") for (int dt = 0; dt < 4; ++dt) ACC[dt][rr] *= alv;   \
      }                                                                        \
    }                                                                          \
    float p[4][4];                                                             \
    _Pragma("unroll") for (int ct = 0; ct < 4; ++ct)                           \
        _Pragma("unroll") for (int rr = 0; rr < 4; ++rr)                       \
            p[ct][rr] = exp2f(vv[ct][rr] - (MROW));                            \
    float ps = (((p[0][0] + p[0][1]) + (p[0][2] + p[0][3])) +                  \
                ((p[1][0] + p[1][1]) + (p[1][2] + p[1][3]))) +                 \
               (((p[2][0] + p[2][1]) + (p[2][2] + p[2][3])) +                  \
                ((p[3][0] + p[3][1]) + (p[3][2] + p[3][3])));                  \
    ps += __shfl_xor(ps, 16);                                                  \
    ps += __shfl_xor(ps, 32);                                                  \
    (LSUM) += ps;                                                              \
    u16* PsB = &Ps[w][0];                                                      \
    _Pragma("unroll") for (int ct = 0; ct < 4; ++ct) {                         \
      u32x2 pw;                                                                \
      pw[0] = cvt_pk_bf16(p[ct][0], p[ct][1]);                                 \
      pw[1] = cvt_pk_bf16(p[ct][2], p[ct][3]);                                 \
      const int pb = (lr * 128 + ct * 32 + lg * 8) ^ swz;                      \
      *(u32x2*)((char*)PsB + pb) = pw;                                         \
    }                                                                          \
    const u16x8 pa0 = *(const u16x8*)((char*)PsB + ((lr * 128 + lg * 16) ^ swz));      \
    const u16x8 pa1 = *(const u16x8*)((char*)PsB + ((lr * 128 + 64 + lg * 16) ^ swz)); \
    __builtin_amdgcn_s_setprio(1);                                             \
    _Pragma("unroll") for (int dt = 0; dt < 4; ++dt) {                         \
      const int r0 = (dt * 16 + lr) * 128;                                     \
      ACC[dt] = mfma16(pa0, *(const u16x8*)((char*)VsC + ((r0 + lg * 16) ^ swz)), ACC[dt]);      \
      ACC[dt] = mfma16(pa1, *(const u16x8*)((char*)VsC + ((r0 + 64 + lg * 16) ^ swz)), ACC[dt]); \
    }                                                                          \
    __builtin_amdgcn_s_setprio(0);                                             \
  } while (0)

  int cur = 0;
  const int nst = qbA + 1;
  for (int st = 0; st < nst; ++st) {
    const int kv0 = st << 6;
    const bool more = st + 1 < nst;
    if (more) {
      const int nv0 = kv0 + 64;
      kr0 = *(const u16x8*)(Kh + (size_t)(nv0 + sr) * 64 + scb * 8);
      kr1 = *(const u16x8*)(Kh + (size_t)(nv0 + 32 + sr) * 64 + scb * 8);
      vr0 = *(const u16x8*)(Vh + (size_t)sr * 2048 + nv0 + scb * 8);
      vr1 = *(const u16x8*)(Vh + (size_t)(32 + sr) * 2048 + nv0 + scb * 8);
    }
    int4 pv4[4];
#pragma unroll
    for (int ct = 0; ct < 4; ++ct)
      pv4[ct] = *(const int4*)(padb + kv0 + ct * 16 + lg * 4);
    const int pall = pv4[0].x & pv4[0].y & pv4[0].z & pv4[0].w &
                     pv4[1].x & pv4[1].y & pv4[1].z & pv4[1].w &
                     pv4[2].x & pv4[2].y & pv4[2].z & pv4[2].w &
                     pv4[3].x & pv4[3].y & pv4[3].z & pv4[3].w;
    const bool allpad = __all(pall != 0);

    const u16* KsC = Ks[cur];
    const u16* VsC = Vs[cur];

    PROCESS(qfA, accA, mrowA, lsumA, qwaveA);       // hi tile: active all steps
    if (st <= qbB)
      PROCESS(qfB, accB, mrowB, lsumB, qwaveB);     // lo tile: shares K/V stage

    if (more) {
      u16* Kn = Ks[cur ^ 1];
      u16* Vn = Vs[cur ^ 1];
      *(u16x8*)((char*)Kn + sb0) = kr0;
      *(u16x8*)((char*)Kn + sb1) = kr1;
      *(u16x8*)((char*)Vn + sb0) = vr0;
      *(u16x8*)((char*)Vn + sb1) = vr1;
    }
    __syncthreads();
    cur ^= 1;
  }
#undef PROCESS

  // epilogue: out[b][q][h*64+d] = acc/l for both tiles
#pragma unroll
  for (int tile = 0; tile < 2; ++tile) {
    const f32x4* acc = tile ? accB : accA;
    const float lsum = tile ? lsumB : lsumA;
    const int qwave = tile ? qwaveB : qwaveA;
    const float il = 1.0f / lsum;
    float* obase = out + ((size_t)(b * 2048 + qwave + lg * 4)) * 1024 + h * 64 + lr;
#pragma unroll
    for (int r = 0; r < 4; ++r) {
      const float linv = bperm_f(lg * 4 + r, il);
#pragma unroll
      for (int dt = 0; dt < 4; ++dt)
        obase[(size_t)r * 1024 + dt * 16] = acc[dt][r] * linv;
    }
  }
}

extern "C" void kernel_launch(void* const* d_in, const int* in_sizes, int n_in,
                              void* d_out, int out_size, void* d_ws, size_t ws_size,
                              hipStream_t stream) {
  const float* q  = (const float*)d_in[0];
  const float* k  = (const float*)d_in[1];
  const float* v  = (const float*)d_in[2];
  const float* wq = (const float*)d_in[3];
  const float* wk = (const float*)d_in[4];
  const float* wv = (const float*)d_in[5];
  const int* pad  = (const int*)d_in[6];
  float* out = (float*)d_out;

  u16* Qb  = (u16*)d_ws;                    // [B,H,S,64] bf16, pre-scaled (8MB)
  u16* Kb  = Qb + (size_t)4 * 1024 * 1024;  // [B,H,S,64] bf16 (8MB)
  u16* Vt  = Kb + (size_t)4 * 1024 * 1024;  // [B,H,64,S] bf16 (8MB)
  u16* Wbf = Vt + (size_t)4 * 1024 * 1024;  // [3][1024][1024] bf16 (6MB)

  dim3 gc(512, 3);
  wconv_kernel<<<gc, 256, 0, stream>>>(wq, wk, wv, Wbf);

  proj_kernel<<<768, 256, 0, stream>>>(q, k, v, Wbf, Qb, Kb, Vt);

  attn_kernel<<<512, 256, 0, stream>>>(Qb, Kb, Vt, pad, out);
}